// Round 1
// baseline (2530.239 us; speedup 1.0000x reference)
//
#include <hip/hip_runtime.h>
#include <hip/hip_bf16.h>

// ---------- types ----------
typedef __attribute__((ext_vector_type(8))) short bf16x8;
typedef __attribute__((ext_vector_type(4))) float f32x4;

__device__ __forceinline__ short f2b(float f) {
    // fp32 -> bf16 round-to-nearest-even
    unsigned u = __builtin_bit_cast(unsigned, f);
    unsigned r = (u + 0x7fffu + ((u >> 16) & 1u)) >> 16;
    return (short)r;
}

// =====================================================================
// Fused MLP: z0 = relu(x @ W_in^T + b_in) @ W_out^T + b_out
// x:[M,512] W_in:[256,512] W_out:[64,256]  -> z0:[M,64]
// Block = 256 threads (4 waves), BM = 64 rows. h kept in LDS (bf16).
// mfma_f32_16x16x32_bf16 layouts (verified, learn_hip m89/m91):
//   A: lane holds A[m=lane&15][k=(lane>>4)*8+j]
//   B (from B^T row-major [N,K]): lane holds Bt[n=lane&15][k=(lane>>4)*8+j]
//   D: row=(lane>>4)*4+r, col=lane&15
// =====================================================================
__global__ __launch_bounds__(256) void fused_linear(
    const float* __restrict__ x, const float* __restrict__ W_in,
    const float* __restrict__ b_in, const float* __restrict__ W_out,
    const float* __restrict__ b_out, float* __restrict__ z0, int M)
{
    __shared__ __align__(16) char smem[65536];
    // stage1 region [0,32768): At [64][40] @0 (5120 B), Bt [256][40] @5120 (20480 B)
    // stage2 region [0,32768): Wo2 [8][4][64][8]  (32768 B, k-blocked, conflict-free)
    // Hs2 region [32768,65536): [8][4][64][8]
    short* At = (short*)smem;
    short* Bt = (short*)(smem + 5120);
    short* Wo = (short*)smem;
    short* Hs = (short*)(smem + 32768);

    const int tid  = threadIdx.x;
    const int lane = tid & 63;
    const int w    = tid >> 6;
    const int row0 = blockIdx.x * 64;

    f32x4 acc[16];
#pragma unroll
    for (int t = 0; t < 16; ++t) { acc[t][0]=0.f; acc[t][1]=0.f; acc[t][2]=0.f; acc[t][3]=0.f; }

    const int f4 = tid & 7;
    for (int kk = 0; kk < 16; ++kk) {      // K1 = 512, 32 per step
        __syncthreads();
        // stage A tile: x[row0..row0+63][kk*32..+32] -> bf16
#pragma unroll
        for (int p = 0; p < 2; ++p) {
            int row = (tid >> 3) + p * 32;
            int grow = row0 + row;
            float4 v = make_float4(0.f, 0.f, 0.f, 0.f);
            if (grow < M) v = *(const float4*)(x + (size_t)grow * 512 + kk * 32 + f4 * 4);
            short* d = At + row * 40 + f4 * 4;
            d[0] = f2b(v.x); d[1] = f2b(v.y); d[2] = f2b(v.z); d[3] = f2b(v.w);
        }
        // stage B tile: W_in[0..255][kk*32..+32]
#pragma unroll
        for (int p = 0; p < 8; ++p) {
            int row = (tid >> 3) + p * 32;
            float4 v = *(const float4*)(W_in + (size_t)row * 512 + kk * 32 + f4 * 4);
            short* d = Bt + row * 40 + f4 * 4;
            d[0] = f2b(v.x); d[1] = f2b(v.y); d[2] = f2b(v.z); d[3] = f2b(v.w);
        }
        __syncthreads();
        bf16x8 a = *(const bf16x8*)(At + (16 * w + (lane & 15)) * 40 + (lane >> 4) * 8);
#pragma unroll
        for (int t = 0; t < 16; ++t) {
            bf16x8 b = *(const bf16x8*)(Bt + (16 * t + (lane & 15)) * 40 + (lane >> 4) * 8);
            acc[t] = __builtin_amdgcn_mfma_f32_16x16x32_bf16(a, b, acc[t], 0, 0, 0);
        }
    }
    __syncthreads();
    // bias + relu -> Hs (bf16, k-blocked layout)
#pragma unroll
    for (int t = 0; t < 16; ++t) {
        int col = 16 * t + (lane & 15);
        float bv = b_in[col];
        int kk2 = col >> 5, q = (col >> 3) & 3, j = col & 7;
#pragma unroll
        for (int r = 0; r < 4; ++r) {
            int row = 16 * w + (lane >> 4) * 4 + r;
            float h = acc[t][r] + bv;
            h = h > 0.f ? h : 0.f;
            Hs[((kk2 * 4 + q) * 64 + row) * 8 + j] = f2b(h);
        }
    }
    // stage W_out -> Wo (bf16, k-blocked layout)
#pragma unroll
    for (int p = 0; p < 16; ++p) {
        int idx4 = tid + p * 256;            // 4096 float4s total
        int row = idx4 >> 6, c0 = (idx4 & 63) * 4;
        float4 v = *(const float4*)(W_out + row * 256 + c0);
        int kk2 = c0 >> 5, q = (c0 >> 3) & 3, j0 = c0 & 7;
        short* d = Wo + ((kk2 * 4 + q) * 64 + row) * 8 + j0;
        d[0] = f2b(v.x); d[1] = f2b(v.y); d[2] = f2b(v.z); d[3] = f2b(v.w);
    }
    __syncthreads();
    // stage 2: z0_tile = Hs @ W_out^T
    f32x4 acc2[4];
#pragma unroll
    for (int t = 0; t < 4; ++t) { acc2[t][0]=0.f; acc2[t][1]=0.f; acc2[t][2]=0.f; acc2[t][3]=0.f; }
#pragma unroll
    for (int kk2 = 0; kk2 < 8; ++kk2) {      // K2 = 256
        bf16x8 a = *(const bf16x8*)(Hs + ((kk2 * 4 + (lane >> 4)) * 64 + 16 * w + (lane & 15)) * 8);
#pragma unroll
        for (int t = 0; t < 4; ++t) {
            bf16x8 b = *(const bf16x8*)(Wo + ((kk2 * 4 + (lane >> 4)) * 64 + 16 * t + (lane & 15)) * 8);
            acc2[t] = __builtin_amdgcn_mfma_f32_16x16x32_bf16(a, b, acc2[t], 0, 0, 0);
        }
    }
#pragma unroll
    for (int t = 0; t < 4; ++t) {
        int col = 16 * t + (lane & 15);
        float bv = b_out[col];
#pragma unroll
        for (int r = 0; r < 4; ++r) {
            int grow = row0 + 16 * w + (lane >> 4) * 4 + r;
            if (grow < M) z0[(size_t)grow * 64 + col] = acc2[t][r] + bv;
        }
    }
}

// =====================================================================
// CSR build (by dst): histogram -> 3-phase exclusive scan -> scatter
// =====================================================================
__global__ void hist_kernel(const int* __restrict__ dst, int* __restrict__ deg, int E)
{
    int e = blockIdx.x * blockDim.x + threadIdx.x;
    if (e < E) atomicAdd(&deg[dst[e]], 1);
}

__global__ __launch_bounds__(1024) void scan1(const int* __restrict__ deg,
                                              int* __restrict__ rowptr,
                                              int* __restrict__ bsums, int n)
{
    __shared__ int wsum[16];
    int tid = threadIdx.x, lane = tid & 63, wid = tid >> 6;
    int gid = blockIdx.x * 1024 + tid;
    int v = (gid < n) ? deg[gid] : 0;
    int xv = v;
#pragma unroll
    for (int off = 1; off < 64; off <<= 1) { int y = __shfl_up(xv, off); if (lane >= off) xv += y; }
    if (lane == 63) wsum[wid] = xv;
    __syncthreads();
    if (wid == 0) {
        int s = (lane < 16) ? wsum[lane] : 0;
#pragma unroll
        for (int off = 1; off < 16; off <<= 1) { int y = __shfl_up(s, off); if (lane >= off) s += y; }
        if (lane < 16) wsum[lane] = s;
    }
    __syncthreads();
    int base = (wid > 0) ? wsum[wid - 1] : 0;
    int incl = xv + base;
    if (gid < n) rowptr[gid] = incl - v;          // exclusive within block
    if (tid == 1023) bsums[blockIdx.x] = incl;    // block total
}

__global__ __launch_bounds__(1024) void scan2(int* __restrict__ b, int nb)
{
    __shared__ int wsum[16];
    int tid = threadIdx.x, lane = tid & 63, wid = tid >> 6;
    int v = (tid < nb) ? b[tid] : 0;
    int xv = v;
#pragma unroll
    for (int off = 1; off < 64; off <<= 1) { int y = __shfl_up(xv, off); if (lane >= off) xv += y; }
    if (lane == 63) wsum[wid] = xv;
    __syncthreads();
    if (wid == 0) {
        int s = (lane < 16) ? wsum[lane] : 0;
#pragma unroll
        for (int off = 1; off < 16; off <<= 1) { int y = __shfl_up(s, off); if (lane >= off) s += y; }
        if (lane < 16) wsum[lane] = s;
    }
    __syncthreads();
    int base = (wid > 0) ? wsum[wid - 1] : 0;
    if (tid < nb) b[tid] = xv + base - v;         // exclusive
}

__global__ __launch_bounds__(1024) void scan3(int* __restrict__ rowptr, int* __restrict__ cursor,
                                              const int* __restrict__ bsums, int n, int E)
{
    int gid = blockIdx.x * 1024 + threadIdx.x;
    if (gid < n) {
        int r = rowptr[gid] + bsums[blockIdx.x];
        rowptr[gid] = r;
        cursor[gid] = r;
    }
    if (gid == 0) rowptr[n] = E;
}

__global__ void scatter_kernel(const int* __restrict__ src, const int* __restrict__ dst,
                               const float* __restrict__ ew, int* __restrict__ cursor,
                               int* __restrict__ csr_src, float* __restrict__ csr_w, int E)
{
    int e = blockIdx.x * blockDim.x + threadIdx.x;
    if (e < E) {
        int d = dst[e];
        int pos = atomicAdd(&cursor[d], 1);
        csr_src[pos] = src[e];
        csr_w[pos]   = ew[e];
    }
}

// =====================================================================
// Propagation: zout[n] = 0.9 * sum_e w_e * zin[src_e] + 0.1 * z0[n]
// One wave per node; 64 lanes = 64 channels; shfl-broadcast edge data.
// =====================================================================
__global__ __launch_bounds__(256) void prop_kernel(
    const int* __restrict__ rowptr, const int* __restrict__ csr_src,
    const float* __restrict__ csr_w, const float* __restrict__ zin,
    const float* __restrict__ z0, float* __restrict__ zout, int n)
{
    int lane = threadIdx.x & 63;
    int node = blockIdx.x * 4 + (threadIdx.x >> 6);
    if (node >= n) return;
    int beg = rowptr[node], end = rowptr[node + 1];
    float acc = 0.f;
    for (int b = beg; b < end; b += 64) {
        int e = b + lane;
        bool ok = (e < end);
        int   s  = ok ? csr_src[e] : 0;
        float wt = ok ? csr_w[e]   : 0.f;
        int cnt = end - b; if (cnt > 64) cnt = 64;
        for (int j = 0; j < cnt; ++j) {
            int   sj = __shfl(s, j);
            float wj = __shfl(wt, j);
            acc += wj * zin[(size_t)sj * 64 + lane];
        }
    }
    zout[(size_t)node * 64 + lane] = 0.9f * acc + 0.1f * z0[(size_t)node * 64 + lane];
}

// =====================================================================
static inline size_t align_up(size_t v, size_t a) { return (v + a - 1) & ~(a - 1); }

extern "C" void kernel_launch(void* const* d_in, const int* in_sizes, int n_in,
                              void* d_out, int out_size, void* d_ws, size_t ws_size,
                              hipStream_t stream)
{
    const float* x     = (const float*)d_in[0];
    const float* W_in  = (const float*)d_in[1];
    const float* b_in  = (const float*)d_in[2];
    const float* W_out = (const float*)d_in[3];
    const float* b_out = (const float*)d_in[4];
    const int*   ei    = (const int*)d_in[5];     // [2,E]: src then dst
    const float* ew    = (const float*)d_in[6];

    const int N = in_sizes[0] / 512;              // 100000
    const int E = in_sizes[6];                    // 3200000
    const int* e_src = ei;
    const int* e_dst = ei + E;

    // ---- workspace carve-up ----
    char* p = (char*)d_ws;
    size_t zbytes = align_up((size_t)N * 64 * sizeof(float), 256);
    float* z0 = (float*)p; p += zbytes;
    float* zA = (float*)p; p += zbytes;
    float* zB = (float*)p; p += zbytes;
    int* deg    = (int*)p; p += align_up((size_t)(N + 1) * 4, 256);
    int* rowptr = (int*)p; p += align_up((size_t)(N + 1) * 4, 256);
    int* cursor = (int*)p; p += align_up((size_t)N * 4, 256);
    int* bsums  = (int*)p; p += align_up(1024 * 4, 256);
    int*   csr_src = (int*)p;   p += align_up((size_t)E * 4, 256);
    float* csr_w   = (float*)p; p += align_up((size_t)E * 4, 256);

    // ---- MLP -> z0 ----
    fused_linear<<<(N + 63) / 64, 256, 0, stream>>>(x, W_in, b_in, W_out, b_out, z0, N);

    // ---- CSR build ----
    hipMemsetAsync(deg, 0, (size_t)N * 4, stream);
    hist_kernel<<<(E + 255) / 256, 256, 0, stream>>>(e_dst, deg, E);
    int nb = (N + 1023) / 1024;
    scan1<<<nb, 1024, 0, stream>>>(deg, rowptr, bsums, N);
    scan2<<<1, 1024, 0, stream>>>(bsums, nb);
    scan3<<<nb, 1024, 0, stream>>>(rowptr, cursor, bsums, N, E);
    scatter_kernel<<<(E + 255) / 256, 256, 0, stream>>>(e_src, e_dst, ew, cursor, csr_src, csr_w, E);

    // ---- 10 propagation layers ----
    float* out_f = (float*)d_out;
    int pgrid = (N + 3) / 4;
    for (int i = 0; i < 10; ++i) {
        const float* zin = (i == 0) ? z0 : ((i & 1) ? zA : zB);  // out[i-1]
        float* zout = (i == 9) ? out_f : ((i & 1) ? zB : zA);
        prop_kernel<<<pgrid, 256, 0, stream>>>(rowptr, csr_src, csr_w, zin, z0, zout, N);
    }
}

// Round 2
// 1858.775 us; speedup vs baseline: 1.3612x; 1.3612x over previous
//
#include <hip/hip_runtime.h>
#include <hip/hip_bf16.h>

// ---------- types ----------
typedef __attribute__((ext_vector_type(8))) short bf16x8;
typedef __attribute__((ext_vector_type(4))) float f32x4;

__device__ __forceinline__ short f2b(float f) {
    // fp32 -> bf16 round-to-nearest-even
    unsigned u = __builtin_bit_cast(unsigned, f);
    unsigned r = (u + 0x7fffu + ((u >> 16) & 1u)) >> 16;
    return (short)r;
}

// =====================================================================
// Fused MLP: z0 = relu(x @ W_in^T + b_in) @ W_out^T + b_out
// x:[M,512] W_in:[256,512] W_out:[64,256]  -> z0:[M,64]
// Block = 256 threads (4 waves), BM = 64 rows. h kept in LDS (bf16).
// =====================================================================
__global__ __launch_bounds__(256) void fused_linear(
    const float* __restrict__ x, const float* __restrict__ W_in,
    const float* __restrict__ b_in, const float* __restrict__ W_out,
    const float* __restrict__ b_out, float* __restrict__ z0, int M)
{
    __shared__ __align__(16) char smem[65536];
    short* At = (short*)smem;
    short* Bt = (short*)(smem + 5120);
    short* Wo = (short*)smem;
    short* Hs = (short*)(smem + 32768);

    const int tid  = threadIdx.x;
    const int lane = tid & 63;
    const int w    = tid >> 6;
    const int row0 = blockIdx.x * 64;

    f32x4 acc[16];
#pragma unroll
    for (int t = 0; t < 16; ++t) { acc[t][0]=0.f; acc[t][1]=0.f; acc[t][2]=0.f; acc[t][3]=0.f; }

    const int f4 = tid & 7;
    for (int kk = 0; kk < 16; ++kk) {      // K1 = 512, 32 per step
        __syncthreads();
#pragma unroll
        for (int p = 0; p < 2; ++p) {
            int row = (tid >> 3) + p * 32;
            int grow = row0 + row;
            float4 v = make_float4(0.f, 0.f, 0.f, 0.f);
            if (grow < M) v = *(const float4*)(x + (size_t)grow * 512 + kk * 32 + f4 * 4);
            short* d = At + row * 40 + f4 * 4;
            d[0] = f2b(v.x); d[1] = f2b(v.y); d[2] = f2b(v.z); d[3] = f2b(v.w);
        }
#pragma unroll
        for (int p = 0; p < 8; ++p) {
            int row = (tid >> 3) + p * 32;
            float4 v = *(const float4*)(W_in + (size_t)row * 512 + kk * 32 + f4 * 4);
            short* d = Bt + row * 40 + f4 * 4;
            d[0] = f2b(v.x); d[1] = f2b(v.y); d[2] = f2b(v.z); d[3] = f2b(v.w);
        }
        __syncthreads();
        bf16x8 a = *(const bf16x8*)(At + (16 * w + (lane & 15)) * 40 + (lane >> 4) * 8);
#pragma unroll
        for (int t = 0; t < 16; ++t) {
            bf16x8 b = *(const bf16x8*)(Bt + (16 * t + (lane & 15)) * 40 + (lane >> 4) * 8);
            acc[t] = __builtin_amdgcn_mfma_f32_16x16x32_bf16(a, b, acc[t], 0, 0, 0);
        }
    }
    __syncthreads();
#pragma unroll
    for (int t = 0; t < 16; ++t) {
        int col = 16 * t + (lane & 15);
        float bv = b_in[col];
        int kk2 = col >> 5, q = (col >> 3) & 3, j = col & 7;
#pragma unroll
        for (int r = 0; r < 4; ++r) {
            int row = 16 * w + (lane >> 4) * 4 + r;
            float h = acc[t][r] + bv;
            h = h > 0.f ? h : 0.f;
            Hs[((kk2 * 4 + q) * 64 + row) * 8 + j] = f2b(h);
        }
    }
#pragma unroll
    for (int p = 0; p < 16; ++p) {
        int idx4 = tid + p * 256;
        int row = idx4 >> 6, c0 = (idx4 & 63) * 4;
        float4 v = *(const float4*)(W_out + row * 256 + c0);
        int kk2 = c0 >> 5, q = (c0 >> 3) & 3, j0 = c0 & 7;
        short* d = Wo + ((kk2 * 4 + q) * 64 + row) * 8 + j0;
        d[0] = f2b(v.x); d[1] = f2b(v.y); d[2] = f2b(v.z); d[3] = f2b(v.w);
    }
    __syncthreads();
    f32x4 acc2[4];
#pragma unroll
    for (int t = 0; t < 4; ++t) { acc2[t][0]=0.f; acc2[t][1]=0.f; acc2[t][2]=0.f; acc2[t][3]=0.f; }
#pragma unroll
    for (int kk2 = 0; kk2 < 8; ++kk2) {
        bf16x8 a = *(const bf16x8*)(Hs + ((kk2 * 4 + (lane >> 4)) * 64 + 16 * w + (lane & 15)) * 8);
#pragma unroll
        for (int t = 0; t < 4; ++t) {
            bf16x8 b = *(const bf16x8*)(Wo + ((kk2 * 4 + (lane >> 4)) * 64 + 16 * t + (lane & 15)) * 8);
            acc2[t] = __builtin_amdgcn_mfma_f32_16x16x32_bf16(a, b, acc2[t], 0, 0, 0);
        }
    }
#pragma unroll
    for (int t = 0; t < 4; ++t) {
        int col = 16 * t + (lane & 15);
        float bv = b_out[col];
#pragma unroll
        for (int r = 0; r < 4; ++r) {
            int grow = row0 + 16 * w + (lane >> 4) * 4 + r;
            if (grow < M) z0[(size_t)grow * 64 + col] = acc2[t][r] + bv;
        }
    }
}

// =====================================================================
// CSR build (by dst): histogram -> 3-phase exclusive scan -> scatter
// =====================================================================
__global__ void hist_kernel(const int* __restrict__ dst, int* __restrict__ deg, int E)
{
    int e = blockIdx.x * blockDim.x + threadIdx.x;
    if (e < E) atomicAdd(&deg[dst[e]], 1);
}

__global__ __launch_bounds__(1024) void scan1(const int* __restrict__ deg,
                                              int* __restrict__ rowptr,
                                              int* __restrict__ bsums, int n)
{
    __shared__ int wsum[16];
    int tid = threadIdx.x, lane = tid & 63, wid = tid >> 6;
    int gid = blockIdx.x * 1024 + tid;
    int v = (gid < n) ? deg[gid] : 0;
    int xv = v;
#pragma unroll
    for (int off = 1; off < 64; off <<= 1) { int y = __shfl_up(xv, off); if (lane >= off) xv += y; }
    if (lane == 63) wsum[wid] = xv;
    __syncthreads();
    if (wid == 0) {
        int s = (lane < 16) ? wsum[lane] : 0;
#pragma unroll
        for (int off = 1; off < 16; off <<= 1) { int y = __shfl_up(s, off); if (lane >= off) s += y; }
        if (lane < 16) wsum[lane] = s;
    }
    __syncthreads();
    int base = (wid > 0) ? wsum[wid - 1] : 0;
    int incl = xv + base;
    if (gid < n) rowptr[gid] = incl - v;
    if (tid == 1023) bsums[blockIdx.x] = incl;
}

__global__ __launch_bounds__(1024) void scan2(int* __restrict__ b, int nb)
{
    __shared__ int wsum[16];
    int tid = threadIdx.x, lane = tid & 63, wid = tid >> 6;
    int v = (tid < nb) ? b[tid] : 0;
    int xv = v;
#pragma unroll
    for (int off = 1; off < 64; off <<= 1) { int y = __shfl_up(xv, off); if (lane >= off) xv += y; }
    if (lane == 63) wsum[wid] = xv;
    __syncthreads();
    if (wid == 0) {
        int s = (lane < 16) ? wsum[lane] : 0;
#pragma unroll
        for (int off = 1; off < 16; off <<= 1) { int y = __shfl_up(s, off); if (lane >= off) s += y; }
        if (lane < 16) wsum[lane] = s;
    }
    __syncthreads();
    int base = (wid > 0) ? wsum[wid - 1] : 0;
    if (tid < nb) b[tid] = xv + base - v;
}

__global__ __launch_bounds__(1024) void scan3(int* __restrict__ rowptr, int* __restrict__ cursor,
                                              const int* __restrict__ bsums, int n, int E)
{
    int gid = blockIdx.x * 1024 + threadIdx.x;
    if (gid < n) {
        int r = rowptr[gid] + bsums[blockIdx.x];
        rowptr[gid] = r;
        cursor[gid] = r;
    }
    if (gid == 0) rowptr[n] = E;
}

// Packed scatter: one 8B store per edge (src, weight-bits) -> half the
// dirtied cache lines vs two 4B stores to separate arrays.
__global__ void scatter_kernel(const int* __restrict__ src, const int* __restrict__ dst,
                               const float* __restrict__ ew, int* __restrict__ cursor,
                               int2* __restrict__ csr, int E)
{
    int e = blockIdx.x * blockDim.x + threadIdx.x;
    if (e < E) {
        int d = dst[e];
        int pos = atomicAdd(&cursor[d], 1);
        csr[pos] = make_int2(src[e], __builtin_bit_cast(int, ew[e]));
    }
}

// =====================================================================
// Propagation: zout[n] = 0.9 * sum_e w_e * zin[src_e] + 0.1 * z0[n]
// One wave per node. Wave is split 4 sub-groups x 16 lanes: each
// sub-group handles one edge per inner iteration via float4 gathers
// (16B/lane), 4 edges in flight. Butterfly-reduce at the end.
// =====================================================================
__global__ __launch_bounds__(256) void prop_kernel(
    const int* __restrict__ rowptr, const int2* __restrict__ csr,
    const float* __restrict__ zin, const float* __restrict__ z0,
    float* __restrict__ zout, int n)
{
    int lane = threadIdx.x & 63;
    int node = blockIdx.x * 4 + (threadIdx.x >> 6);
    if (node >= n) return;
    int beg = rowptr[node], end = rowptr[node + 1];
    const int sub = lane >> 4;      // edge slot 0..3
    const int c4  = lane & 15;      // float4 index within the 64-ch row

    float4 acc = make_float4(0.f, 0.f, 0.f, 0.f);
    for (int b = beg; b < end; b += 64) {
        int e = b + lane;
        int2 ed = (e < end) ? csr[e] : make_int2(0, 0);   // w-bits 0 -> 0.0f
        int cnt = end - b; if (cnt > 64) cnt = 64;
        int groups = (cnt + 3) >> 2;
        for (int j = 0; j < groups; ++j) {
            int idx = j * 4 + sub;                // which edge of this chunk
            int sj  = __shfl(ed.x, idx);
            int wb  = __shfl(ed.y, idx);
            float wj = __builtin_bit_cast(float, wb);
            float4 v = ((const float4*)(zin + (size_t)sj * 64))[c4];
            acc.x += wj * v.x; acc.y += wj * v.y;
            acc.z += wj * v.z; acc.w += wj * v.w;
        }
    }
    // reduce the 4 sub-group partials (xor-16, xor-32 butterflies)
#pragma unroll
    for (int off = 16; off < 64; off <<= 1) {
        acc.x += __shfl_xor(acc.x, off);
        acc.y += __shfl_xor(acc.y, off);
        acc.z += __shfl_xor(acc.z, off);
        acc.w += __shfl_xor(acc.w, off);
    }
    if (sub == 0) {
        float4 z0v = ((const float4*)(z0 + (size_t)node * 64))[c4];
        float4 o;
        o.x = 0.9f * acc.x + 0.1f * z0v.x;
        o.y = 0.9f * acc.y + 0.1f * z0v.y;
        o.z = 0.9f * acc.z + 0.1f * z0v.z;
        o.w = 0.9f * acc.w + 0.1f * z0v.w;
        ((float4*)(zout + (size_t)node * 64))[c4] = o;
    }
}

// =====================================================================
static inline size_t align_up(size_t v, size_t a) { return (v + a - 1) & ~(a - 1); }

extern "C" void kernel_launch(void* const* d_in, const int* in_sizes, int n_in,
                              void* d_out, int out_size, void* d_ws, size_t ws_size,
                              hipStream_t stream)
{
    const float* x     = (const float*)d_in[0];
    const float* W_in  = (const float*)d_in[1];
    const float* b_in  = (const float*)d_in[2];
    const float* W_out = (const float*)d_in[3];
    const float* b_out = (const float*)d_in[4];
    const int*   ei    = (const int*)d_in[5];     // [2,E]: src then dst
    const float* ew    = (const float*)d_in[6];

    const int N = in_sizes[0] / 512;              // 100000
    const int E = in_sizes[6];                    // 3200000
    const int* e_src = ei;
    const int* e_dst = ei + E;

    // ---- workspace carve-up ----
    char* p = (char*)d_ws;
    size_t zbytes = align_up((size_t)N * 64 * sizeof(float), 256);
    float* z0 = (float*)p; p += zbytes;
    float* zA = (float*)p; p += zbytes;
    float* zB = (float*)p; p += zbytes;
    int* deg    = (int*)p; p += align_up((size_t)(N + 1) * 4, 256);
    int* rowptr = (int*)p; p += align_up((size_t)(N + 1) * 4, 256);
    int* cursor = (int*)p; p += align_up((size_t)N * 4, 256);
    int* bsums  = (int*)p; p += align_up(1024 * 4, 256);
    int2* csr   = (int2*)p; p += align_up((size_t)E * 8, 256);

    // ---- MLP -> z0 ----
    fused_linear<<<(N + 63) / 64, 256, 0, stream>>>(x, W_in, b_in, W_out, b_out, z0, N);

    // ---- CSR build ----
    hipMemsetAsync(deg, 0, (size_t)N * 4, stream);
    hist_kernel<<<(E + 255) / 256, 256, 0, stream>>>(e_dst, deg, E);
    int nb = (N + 1023) / 1024;
    scan1<<<nb, 1024, 0, stream>>>(deg, rowptr, bsums, N);
    scan2<<<1, 1024, 0, stream>>>(bsums, nb);
    scan3<<<nb, 1024, 0, stream>>>(rowptr, cursor, bsums, N, E);
    scatter_kernel<<<(E + 255) / 256, 256, 0, stream>>>(e_src, e_dst, ew, cursor, csr, E);

    // ---- 10 propagation layers ----
    float* out_f = (float*)d_out;
    int pgrid = (N + 3) / 4;
    for (int i = 0; i < 10; ++i) {
        const float* zin = (i == 0) ? z0 : ((i & 1) ? zA : zB);
        float* zout = (i == 9) ? out_f : ((i & 1) ? zB : zA);
        prop_kernel<<<pgrid, 256, 0, stream>>>(rowptr, csr, zin, z0, zout, N);
    }
}

// Round 4
// 1231.255 us; speedup vs baseline: 2.0550x; 1.5097x over previous
//
#include <hip/hip_runtime.h>
#include <hip/hip_bf16.h>

// ---------- types ----------
typedef __attribute__((ext_vector_type(8))) short bf16x8;
typedef __attribute__((ext_vector_type(4))) float f32x4;

__device__ __forceinline__ short f2b(float f) {
    // fp32 -> bf16 round-to-nearest-even
    unsigned u = __builtin_bit_cast(unsigned, f);
    unsigned r = (u + 0x7fffu + ((u >> 16) & 1u)) >> 16;
    return (short)r;
}
__device__ __forceinline__ unsigned f2bu(float f) {
    unsigned u = __builtin_bit_cast(unsigned, f);
    return ((u + 0x7fffu + ((u >> 16) & 1u)) >> 16) & 0xffffu;
}
__device__ __forceinline__ float blo(unsigned u) {
    return __builtin_bit_cast(float, u << 16);
}
__device__ __forceinline__ float bhi(unsigned u) {
    return __builtin_bit_cast(float, u & 0xffff0000u);
}

// =====================================================================
// Fused MLP: z0 = relu(x @ W_in^T + b_in) @ W_out^T + b_out  -> bf16
// =====================================================================
__global__ __launch_bounds__(256) void fused_linear(
    const float* __restrict__ x, const float* __restrict__ W_in,
    const float* __restrict__ b_in, const float* __restrict__ W_out,
    const float* __restrict__ b_out, unsigned short* __restrict__ z0, int M)
{
    __shared__ __align__(16) char smem[65536];
    short* At = (short*)smem;
    short* Bt = (short*)(smem + 5120);
    short* Wo = (short*)smem;
    short* Hs = (short*)(smem + 32768);

    const int tid  = threadIdx.x;
    const int lane = tid & 63;
    const int w    = tid >> 6;
    const int row0 = blockIdx.x * 64;

    f32x4 acc[16];
#pragma unroll
    for (int t = 0; t < 16; ++t) { acc[t][0]=0.f; acc[t][1]=0.f; acc[t][2]=0.f; acc[t][3]=0.f; }

    const int f4 = tid & 7;
    for (int kk = 0; kk < 16; ++kk) {      // K1 = 512, 32 per step
        __syncthreads();
#pragma unroll
        for (int p = 0; p < 2; ++p) {
            int row = (tid >> 3) + p * 32;
            int grow = row0 + row;
            float4 v = make_float4(0.f, 0.f, 0.f, 0.f);
            if (grow < M) v = *(const float4*)(x + (size_t)grow * 512 + kk * 32 + f4 * 4);
            short* d = At + row * 40 + f4 * 4;
            d[0] = f2b(v.x); d[1] = f2b(v.y); d[2] = f2b(v.z); d[3] = f2b(v.w);
        }
#pragma unroll
        for (int p = 0; p < 8; ++p) {
            int row = (tid >> 3) + p * 32;
            float4 v = *(const float4*)(W_in + (size_t)row * 512 + kk * 32 + f4 * 4);
            short* d = Bt + row * 40 + f4 * 4;
            d[0] = f2b(v.x); d[1] = f2b(v.y); d[2] = f2b(v.z); d[3] = f2b(v.w);
        }
        __syncthreads();
        bf16x8 a = *(const bf16x8*)(At + (16 * w + (lane & 15)) * 40 + (lane >> 4) * 8);
#pragma unroll
        for (int t = 0; t < 16; ++t) {
            bf16x8 b = *(const bf16x8*)(Bt + (16 * t + (lane & 15)) * 40 + (lane >> 4) * 8);
            acc[t] = __builtin_amdgcn_mfma_f32_16x16x32_bf16(a, b, acc[t], 0, 0, 0);
        }
    }
    __syncthreads();
#pragma unroll
    for (int t = 0; t < 16; ++t) {
        int col = 16 * t + (lane & 15);
        float bv = b_in[col];
        int kk2 = col >> 5, q = (col >> 3) & 3, j = col & 7;
#pragma unroll
        for (int r = 0; r < 4; ++r) {
            int row = 16 * w + (lane >> 4) * 4 + r;
            float h = acc[t][r] + bv;
            h = h > 0.f ? h : 0.f;
            Hs[((kk2 * 4 + q) * 64 + row) * 8 + j] = f2b(h);
        }
    }
#pragma unroll
    for (int p = 0; p < 16; ++p) {
        int idx4 = tid + p * 256;
        int row = idx4 >> 6, c0 = (idx4 & 63) * 4;
        float4 v = *(const float4*)(W_out + row * 256 + c0);
        int kk2 = c0 >> 5, q = (c0 >> 3) & 3, j0 = c0 & 7;
        short* d = Wo + ((kk2 * 4 + q) * 64 + row) * 8 + j0;
        d[0] = f2b(v.x); d[1] = f2b(v.y); d[2] = f2b(v.z); d[3] = f2b(v.w);
    }
    __syncthreads();
    f32x4 acc2[4];
#pragma unroll
    for (int t = 0; t < 4; ++t) { acc2[t][0]=0.f; acc2[t][1]=0.f; acc2[t][2]=0.f; acc2[t][3]=0.f; }
#pragma unroll
    for (int kk2 = 0; kk2 < 8; ++kk2) {
        bf16x8 a = *(const bf16x8*)(Hs + ((kk2 * 4 + (lane >> 4)) * 64 + 16 * w + (lane & 15)) * 8);
#pragma unroll
        for (int t = 0; t < 4; ++t) {
            bf16x8 b = *(const bf16x8*)(Wo + ((kk2 * 4 + (lane >> 4)) * 64 + 16 * t + (lane & 15)) * 8);
            acc2[t] = __builtin_amdgcn_mfma_f32_16x16x32_bf16(a, b, acc2[t], 0, 0, 0);
        }
    }
#pragma unroll
    for (int t = 0; t < 4; ++t) {
        int col = 16 * t + (lane & 15);
        float bv = b_out[col];
#pragma unroll
        for (int r = 0; r < 4; ++r) {
            int grow = row0 + 16 * w + (lane >> 4) * 4 + r;
            if (grow < M) z0[(size_t)grow * 64 + col] = (unsigned short)f2bu(acc2[t][r] + bv);
        }
    }
}

// =====================================================================
// CSR build: 2-level counting sort by dst.
//   coarse buckets = 512 nodes each (bucket = dst >> 9)
//   M layout: [NBLK][NBUK] counts -> (in-place) running offsets
// =====================================================================
#define CSR_CH   16384        // edges per chunk (block) in coarse pass
#define MAXBUK   256          // >= NBUK = ceil(N/512) = 196

__global__ __launch_bounds__(256) void coarse_hist(
    const int* __restrict__ dst, int* __restrict__ M, int E, int nbuk)
{
    __shared__ int cnt[MAXBUK];
    int tid = threadIdx.x, blk = blockIdx.x;
    for (int i = tid; i < nbuk; i += 256) cnt[i] = 0;
    __syncthreads();
    int e0 = blk * CSR_CH, e1 = e0 + CSR_CH; if (e1 > E) e1 = E;
    for (int e = e0 + tid; e < e1; e += 256) atomicAdd(&cnt[dst[e] >> 9], 1);
    __syncthreads();
    for (int i = tid; i < nbuk; i += 256) M[blk * nbuk + i] = cnt[i];
}

__global__ __launch_bounds__(256) void bucket_scan(
    int* __restrict__ M, int* __restrict__ bucketBase, int nblk, int nbuk)
{
    __shared__ int tot[MAXBUK];
    int tid = threadIdx.x;
    // column totals (coalesced: thread r strides rows)
    for (int r = tid; r < nbuk; r += 256) {
        int s = 0;
        for (int k = 0; k < nblk; ++k) s += M[k * nbuk + r];
        tot[r] = s;
    }
    __syncthreads();
    if (tid == 0) {
        int s = 0;
        for (int r = 0; r < nbuk; ++r) { int t = tot[r]; tot[r] = s; bucketBase[r] = s; s += t; }
        bucketBase[nbuk] = s;
    }
    __syncthreads();
    // per-column running offsets, in place
    for (int r = tid; r < nbuk; r += 256) {
        int s = tot[r];
        for (int k = 0; k < nblk; ++k) { int t = M[k * nbuk + r]; M[k * nbuk + r] = s; s += t; }
    }
}

__global__ __launch_bounds__(256) void coarse_scatter(
    const int* __restrict__ src, const int* __restrict__ dst,
    const float* __restrict__ ew, const int* __restrict__ M,
    int4* __restrict__ tmp, int E, int nbuk)
{
    __shared__ int off[MAXBUK];
    int tid = threadIdx.x, blk = blockIdx.x;
    for (int i = tid; i < nbuk; i += 256) off[i] = M[blk * nbuk + i];
    __syncthreads();
    int e0 = blk * CSR_CH, e1 = e0 + CSR_CH; if (e1 > E) e1 = E;
    for (int e = e0 + tid; e < e1; e += 256) {
        int d = dst[e];
        int pos = atomicAdd(&off[d >> 9], 1);
        tmp[pos] = make_int4(src[e], __builtin_bit_cast(int, ew[e]), d, 0);
    }
}

__global__ __launch_bounds__(256) void fine_sort(
    const int4* __restrict__ tmp, const int* __restrict__ bucketBase,
    int2* __restrict__ csr, int* __restrict__ rowptr, int N, int E)
{
    __shared__ int fc[512];
    __shared__ int fo[512];
    __shared__ int wsum[5];
    int b = blockIdx.x, tid = threadIdx.x;
    int base = bucketBase[b], cnt = bucketBase[b + 1] - base;
    int node0 = b << 9;

    fc[tid] = 0; fc[tid + 256] = 0;
    __syncthreads();
    for (int i = tid; i < cnt; i += 256)
        atomicAdd(&fc[tmp[base + i].z - node0], 1);
    __syncthreads();

    // exclusive scan of fc[0..511] -> fo
    int lane = tid & 63, wid = tid >> 6;
    int runbase = 0;
    for (int h = 0; h < 2; ++h) {
        int v = fc[h * 256 + tid];
        int x = v;
#pragma unroll
        for (int off = 1; off < 64; off <<= 1) { int y = __shfl_up(x, off); if (lane >= off) x += y; }
        if (lane == 63) wsum[wid] = x;
        __syncthreads();
        if (tid == 0) { int s = 0; for (int k = 0; k < 4; ++k) { int t = wsum[k]; wsum[k] = s; s += t; } wsum[4] = s; }
        __syncthreads();
        fo[h * 256 + tid] = runbase + wsum[wid] + x - v;
        runbase += wsum[4];
        __syncthreads();
    }

    // rowptr for this bucket's nodes
    for (int i = tid; i < 512; i += 256) {
        int node = node0 + i;
        if (node < N) rowptr[node] = base + fo[i];
    }
    if (b == 0 && tid == 0) rowptr[N] = E;
    __syncthreads();

    // scatter within bucket (fo doubles as live cursors)
    for (int i = tid; i < cnt; i += 256) {
        int4 ed = tmp[base + i];
        int pos = atomicAdd(&fo[ed.z - node0], 1);
        csr[base + pos] = make_int2(ed.x, ed.y);
    }
}

// =====================================================================
// Propagation (bf16 state): zout = 0.9 * A zin + 0.1 * z0
// One wave per node, 8 sub-groups x 8 lanes, 8 edges in flight,
// 16B bf16 gathers per lane. Final layer writes fp32.
// =====================================================================
__global__ __launch_bounds__(256) void prop_kernel(
    const int* __restrict__ rowptr, const int2* __restrict__ csr,
    const unsigned short* __restrict__ zin, const unsigned short* __restrict__ z0,
    unsigned short* __restrict__ zout_b, float* __restrict__ zout_f,
    int n, int final_layer)
{
    int lane = threadIdx.x & 63;
    int node = blockIdx.x * 4 + (threadIdx.x >> 6);
    if (node >= n) return;
    int beg = rowptr[node], end = rowptr[node + 1];
    const int sub = lane >> 3;      // edge slot 0..7
    const int k8  = lane & 7;       // 8-channel group within the 64-ch row

    float acc[8];
#pragma unroll
    for (int i = 0; i < 8; ++i) acc[i] = 0.f;

    for (int b = beg; b < end; b += 64) {
        int e = b + lane;
        int2 ed = (e < end) ? csr[e] : make_int2(0, 0);
        int cnt = end - b; if (cnt > 64) cnt = 64;
        int groups = (cnt + 7) >> 3;
        for (int j = 0; j < groups; ++j) {
            int idx = j * 8 + sub;
            int sj = __shfl(ed.x, idx);
            int wb = __shfl(ed.y, idx);
            if (idx < cnt) {
                float wj = __builtin_bit_cast(float, wb);
                uint4 v = *(const uint4*)(zin + (size_t)sj * 64 + k8 * 8);
                acc[0] += wj * blo(v.x); acc[1] += wj * bhi(v.x);
                acc[2] += wj * blo(v.y); acc[3] += wj * bhi(v.y);
                acc[4] += wj * blo(v.z); acc[5] += wj * bhi(v.z);
                acc[6] += wj * blo(v.w); acc[7] += wj * bhi(v.w);
            }
        }
    }
#pragma unroll
    for (int off = 8; off < 64; off <<= 1) {
#pragma unroll
        for (int i = 0; i < 8; ++i) acc[i] += __shfl_xor(acc[i], off);
    }
    if (sub == 0) {
        uint4 zv = *(const uint4*)(z0 + (size_t)node * 64 + k8 * 8);
        float o0 = 0.9f * acc[0] + 0.1f * blo(zv.x);
        float o1 = 0.9f * acc[1] + 0.1f * bhi(zv.x);
        float o2 = 0.9f * acc[2] + 0.1f * blo(zv.y);
        float o3 = 0.9f * acc[3] + 0.1f * bhi(zv.y);
        float o4 = 0.9f * acc[4] + 0.1f * blo(zv.z);
        float o5 = 0.9f * acc[5] + 0.1f * bhi(zv.z);
        float o6 = 0.9f * acc[6] + 0.1f * blo(zv.w);
        float o7 = 0.9f * acc[7] + 0.1f * bhi(zv.w);
        if (final_layer) {
            float* dp = zout_f + (size_t)node * 64 + k8 * 8;
            *(float4*)dp       = make_float4(o0, o1, o2, o3);
            *(float4*)(dp + 4) = make_float4(o4, o5, o6, o7);
        } else {
            uint4 pv;
            pv.x = f2bu(o0) | (f2bu(o1) << 16);
            pv.y = f2bu(o2) | (f2bu(o3) << 16);
            pv.z = f2bu(o4) | (f2bu(o5) << 16);
            pv.w = f2bu(o6) | (f2bu(o7) << 16);
            *(uint4*)(zout_b + (size_t)node * 64 + k8 * 8) = pv;
        }
    }
}

// =====================================================================
static inline size_t align_up(size_t v, size_t a) { return (v + a - 1) & ~(a - 1); }

extern "C" void kernel_launch(void* const* d_in, const int* in_sizes, int n_in,
                              void* d_out, int out_size, void* d_ws, size_t ws_size,
                              hipStream_t stream)
{
    const float* x     = (const float*)d_in[0];
    const float* W_in  = (const float*)d_in[1];
    const float* b_in  = (const float*)d_in[2];
    const float* W_out = (const float*)d_in[3];
    const float* b_out = (const float*)d_in[4];
    const int*   ei    = (const int*)d_in[5];     // [2,E]: src then dst
    const float* ew    = (const float*)d_in[6];

    const int N = in_sizes[0] / 512;              // 100000
    const int E = in_sizes[6];                    // 3200000
    const int* e_src = ei;
    const int* e_dst = ei + E;

    const int nbuk = (N + 511) >> 9;              // 196
    const int nblk = (E + CSR_CH - 1) / CSR_CH;   // 196

    // ---- workspace carve-up ----
    char* p = (char*)d_ws;
    size_t zbytes = align_up((size_t)N * 64 * sizeof(unsigned short), 256);
    unsigned short* z0b = (unsigned short*)p; p += zbytes;
    int2* csr   = (int2*)p; p += align_up((size_t)E * 8, 256);
    int* rowptr = (int*)p;  p += align_up((size_t)(N + 1) * 4, 256);
    int* M      = (int*)p;  p += align_up((size_t)nblk * nbuk * 4, 256);
    int* bucketBase = (int*)p; p += align_up((size_t)(nbuk + 1) * 4, 256);
    int4* tmp   = (int4*)p; p += align_up((size_t)E * 16, 256);
    // zA/zB overlay tmp (tmp dead after fine_sort)
    unsigned short* zA = (unsigned short*)tmp;
    unsigned short* zB = zA + (size_t)N * 64;

    // ---- MLP -> z0 (bf16) ----
    fused_linear<<<(N + 63) / 64, 256, 0, stream>>>(x, W_in, b_in, W_out, b_out, z0b, N);

    // ---- CSR build: 2-level counting sort ----
    coarse_hist<<<nblk, 256, 0, stream>>>(e_dst, M, E, nbuk);
    bucket_scan<<<1, 256, 0, stream>>>(M, bucketBase, nblk, nbuk);
    coarse_scatter<<<nblk, 256, 0, stream>>>(e_src, e_dst, ew, M, tmp, E, nbuk);
    fine_sort<<<nbuk, 256, 0, stream>>>(tmp, bucketBase, csr, rowptr, N, E);

    // ---- 10 propagation layers ----
    float* out_f = (float*)d_out;
    int pgrid = (N + 3) / 4;
    for (int i = 0; i < 10; ++i) {
        const unsigned short* zin = (i == 0) ? z0b : ((i & 1) ? zA : zB);
        unsigned short* zoutb = (i & 1) ? zB : zA;
        prop_kernel<<<pgrid, 256, 0, stream>>>(rowptr, csr, zin, z0b,
                                               zoutb, out_f, N, (i == 9) ? 1 : 0);
    }
}

// Round 5
// 1181.442 us; speedup vs baseline: 2.1417x; 1.0422x over previous
//
#include <hip/hip_runtime.h>
#include <hip/hip_bf16.h>

// ---------- types ----------
typedef __attribute__((ext_vector_type(8))) short bf16x8;
typedef __attribute__((ext_vector_type(4))) float f32x4;

__device__ __forceinline__ short f2b(float f) {
    unsigned u = __builtin_bit_cast(unsigned, f);
    unsigned r = (u + 0x7fffu + ((u >> 16) & 1u)) >> 16;
    return (short)r;
}
__device__ __forceinline__ unsigned f2bu(float f) {
    unsigned u = __builtin_bit_cast(unsigned, f);
    return ((u + 0x7fffu + ((u >> 16) & 1u)) >> 16) & 0xffffu;
}
__device__ __forceinline__ float blo(unsigned u) {
    return __builtin_bit_cast(float, u << 16);
}
__device__ __forceinline__ float bhi(unsigned u) {
    return __builtin_bit_cast(float, u & 0xffff0000u);
}

// =====================================================================
// Weight pre-conversion: fp32 -> bf16 in MFMA fragment order.
// Wi_f: [kk<16][t<16][lane<64][j<8]  (W_in[n=16t+(lane&15)][k=32kk+8*(lane>>4)+j])
// Wo_f: [kk2<8][t<4][lane<64][j<8]
// =====================================================================
__global__ __launch_bounds__(256) void wprep(
    const float* __restrict__ W_in, const float* __restrict__ W_out,
    unsigned short* __restrict__ Wi_f, unsigned short* __restrict__ Wo_f)
{
    int o = blockIdx.x * 256 + threadIdx.x;
    if (o < 131072) {
        int j = o & 7, lane = (o >> 3) & 63, t = (o >> 9) & 15, kk = o >> 13;
        int n = t * 16 + (lane & 15);
        int k = kk * 32 + ((lane >> 4) << 3) + j;
        Wi_f[o] = (unsigned short)f2bu(W_in[n * 512 + k]);
    } else if (o < 131072 + 16384) {
        int o2 = o - 131072;
        int j = o2 & 7, lane = (o2 >> 3) & 63, t = (o2 >> 9) & 3, kk2 = o2 >> 11;
        int n = t * 16 + (lane & 15);
        int k = kk2 * 32 + ((lane >> 4) << 3) + j;
        Wo_f[o2] = (unsigned short)f2bu(W_out[n * 256 + k]);
    }
}

// =====================================================================
// Fused MLP: z0 = relu(x @ W_in^T + b_in) @ W_out^T + b_out  -> bf16
// Block 256 (4 waves), BM=64.  B staged async (global_load_lds, 16B,
// fragment-ordered -> conflict-free b128 reads).  A converted in regs,
// packed ds_write_b64.  Stage-2 B-frags read from L1-resident global.
// LDS 33 KB -> 4 blocks/CU.
// =====================================================================
__global__ __launch_bounds__(256) void mlp(
    const float* __restrict__ x, const unsigned short* __restrict__ Wi_f,
    const float* __restrict__ b_in, const unsigned short* __restrict__ Wo_f,
    const float* __restrict__ b_out, unsigned short* __restrict__ z0, int M)
{
    __shared__ __align__(16) char smem[33280];
    short* At = (short*)smem;            // [64][40] bf16, padded
    short* Bt = (short*)(smem + 5120);   // frag-ordered [t<16][lane<64][j<8]
    short* Hs = (short*)smem;            // stage2: [qb<32][520]  (8-short pad/qb)

    const int tid  = threadIdx.x;
    const int lane = tid & 63;
    const int w    = tid >> 6;
    const int row0 = blockIdx.x * 64;
    const int c    = lane & 15;
    const int qk   = lane >> 4;

    f32x4 acc[16];
#pragma unroll
    for (int t = 0; t < 16; ++t) { acc[t][0]=0.f; acc[t][1]=0.f; acc[t][2]=0.f; acc[t][3]=0.f; }

    const int f4   = tid & 7;
    const int arow = tid >> 3;           // 0..31
    for (int kk = 0; kk < 16; ++kk) {    // K1 = 512, 32 per step
        __syncthreads();
        // A tile: fp32 load -> packed bf16 -> one b64 LDS write per float4
#pragma unroll
        for (int p = 0; p < 2; ++p) {
            int row = arow + p * 32;
            int grow = row0 + row;
            float4 v = make_float4(0.f, 0.f, 0.f, 0.f);
            if (grow < M) v = *(const float4*)(x + (size_t)grow * 512 + kk * 32 + f4 * 4);
            uint2 pk;
            pk.x = f2bu(v.x) | (f2bu(v.y) << 16);
            pk.y = f2bu(v.z) | (f2bu(v.w) << 16);
            *(uint2*)(At + row * 40 + f4 * 4) = pk;
        }
        // B tile: async DMA, wave w moves chunks t = 4w..4w+3 (1 KB each)
#pragma unroll
        for (int i = 0; i < 4; ++i) {
            int t = w * 4 + i;
            const unsigned short* g = Wi_f + (((size_t)kk * 16 + t) * 64 + lane) * 8;
            __builtin_amdgcn_global_load_lds(
                (const __attribute__((address_space(1))) unsigned int*)g,
                (__attribute__((address_space(3))) unsigned int*)(Bt + t * 512),
                16, 0, 0);
        }
        __syncthreads();
        bf16x8 a = *(const bf16x8*)(At + (16 * w + c) * 40 + qk * 8);
#pragma unroll
        for (int t = 0; t < 16; ++t) {
            bf16x8 b = *(const bf16x8*)(Bt + (t * 64 + lane) * 8);
            acc[t] = __builtin_amdgcn_mfma_f32_16x16x32_bf16(a, b, acc[t], 0, 0, 0);
        }
    }
    __syncthreads();
    // bias + relu -> Hs (bf16, q-padded k-blocked layout)
#pragma unroll
    for (int t = 0; t < 16; ++t) {
        int col = 16 * t + c;
        float bv = b_in[col];
        int qb = col >> 3, j = col & 7;
#pragma unroll
        for (int r = 0; r < 4; ++r) {
            int row = 16 * w + qk * 4 + r;
            float h = acc[t][r] + bv;
            h = h > 0.f ? h : 0.f;
            Hs[qb * 520 + row * 8 + j] = f2b(h);
        }
    }
    __syncthreads();
    // stage 2: z0_tile = Hs @ W_out^T ; B-frags straight from global (L1)
    f32x4 acc2[4];
#pragma unroll
    for (int t = 0; t < 4; ++t) { acc2[t][0]=0.f; acc2[t][1]=0.f; acc2[t][2]=0.f; acc2[t][3]=0.f; }
#pragma unroll
    for (int kk2 = 0; kk2 < 8; ++kk2) {
        bf16x8 a2 = *(const bf16x8*)(Hs + (kk2 * 4 + qk) * 520 + (16 * w + c) * 8);
#pragma unroll
        for (int t = 0; t < 4; ++t) {
            bf16x8 b2 = *(const bf16x8*)(Wo_f + (((size_t)kk2 * 4 + t) * 64 + lane) * 8);
            acc2[t] = __builtin_amdgcn_mfma_f32_16x16x32_bf16(a2, b2, acc2[t], 0, 0, 0);
        }
    }
#pragma unroll
    for (int t = 0; t < 4; ++t) {
        int col = 16 * t + c;
        float bv = b_out[col];
#pragma unroll
        for (int r = 0; r < 4; ++r) {
            int grow = row0 + 16 * w + qk * 4 + r;
            if (grow < M) z0[(size_t)grow * 64 + col] = (unsigned short)f2bu(acc2[t][r] + bv);
        }
    }
}

// =====================================================================
// CSR build: 2-level counting sort by dst.
// =====================================================================
#define CSR_CH   16384
#define MAXBUK   256

__global__ __launch_bounds__(256) void coarse_hist(
    const int* __restrict__ dst, int* __restrict__ M, int E, int nbuk)
{
    __shared__ int cnt[MAXBUK];
    int tid = threadIdx.x, blk = blockIdx.x;
    for (int i = tid; i < nbuk; i += 256) cnt[i] = 0;
    __syncthreads();
    int e0 = blk * CSR_CH, e1 = e0 + CSR_CH; if (e1 > E) e1 = E;
    for (int e = e0 + tid; e < e1; e += 256) atomicAdd(&cnt[dst[e] >> 9], 1);
    __syncthreads();
    for (int i = tid; i < nbuk; i += 256) M[blk * nbuk + i] = cnt[i];
}

__global__ __launch_bounds__(256) void bucket_scan(
    int* __restrict__ M, int* __restrict__ bucketBase, int nblk, int nbuk)
{
    __shared__ int tot[MAXBUK];
    int tid = threadIdx.x;
    for (int r = tid; r < nbuk; r += 256) {
        int s = 0;
        for (int k = 0; k < nblk; ++k) s += M[k * nbuk + r];
        tot[r] = s;
    }
    __syncthreads();
    if (tid == 0) {
        int s = 0;
        for (int r = 0; r < nbuk; ++r) { int t = tot[r]; tot[r] = s; bucketBase[r] = s; s += t; }
        bucketBase[nbuk] = s;
    }
    __syncthreads();
    for (int r = tid; r < nbuk; r += 256) {
        int s = tot[r];
        for (int k = 0; k < nblk; ++k) { int t = M[k * nbuk + r]; M[k * nbuk + r] = s; s += t; }
    }
}

__global__ __launch_bounds__(256) void coarse_scatter(
    const int* __restrict__ src, const int* __restrict__ dst,
    const float* __restrict__ ew, const int* __restrict__ M,
    int4* __restrict__ tmp, int E, int nbuk)
{
    __shared__ int off[MAXBUK];
    int tid = threadIdx.x, blk = blockIdx.x;
    for (int i = tid; i < nbuk; i += 256) off[i] = M[blk * nbuk + i];
    __syncthreads();
    int e0 = blk * CSR_CH, e1 = e0 + CSR_CH; if (e1 > E) e1 = E;
    for (int e = e0 + tid; e < e1; e += 256) {
        int d = dst[e];
        int pos = atomicAdd(&off[d >> 9], 1);
        tmp[pos] = make_int4(src[e], __builtin_bit_cast(int, ew[e]), d, 0);
    }
}

__global__ __launch_bounds__(256) void fine_sort(
    const int4* __restrict__ tmp, const int* __restrict__ bucketBase,
    int2* __restrict__ csr, int* __restrict__ rowptr, int N, int E)
{
    __shared__ int fc[512];
    __shared__ int fo[512];
    __shared__ int wsum[5];
    int b = blockIdx.x, tid = threadIdx.x;
    int base = bucketBase[b], cnt = bucketBase[b + 1] - base;
    int node0 = b << 9;

    fc[tid] = 0; fc[tid + 256] = 0;
    __syncthreads();
    for (int i = tid; i < cnt; i += 256)
        atomicAdd(&fc[tmp[base + i].z - node0], 1);
    __syncthreads();

    int lane = tid & 63, wid = tid >> 6;
    int runbase = 0;
    for (int h = 0; h < 2; ++h) {
        int v = fc[h * 256 + tid];
        int x = v;
#pragma unroll
        for (int off = 1; off < 64; off <<= 1) { int y = __shfl_up(x, off); if (lane >= off) x += y; }
        if (lane == 63) wsum[wid] = x;
        __syncthreads();
        if (tid == 0) { int s = 0; for (int k = 0; k < 4; ++k) { int t = wsum[k]; wsum[k] = s; s += t; } wsum[4] = s; }
        __syncthreads();
        fo[h * 256 + tid] = runbase + wsum[wid] + x - v;
        runbase += wsum[4];
        __syncthreads();
    }

    for (int i = tid; i < 512; i += 256) {
        int node = node0 + i;
        if (node < N) rowptr[node] = base + fo[i];
    }
    if (b == 0 && tid == 0) rowptr[N] = E;
    __syncthreads();

    for (int i = tid; i < cnt; i += 256) {
        int4 ed = tmp[base + i];
        int pos = atomicAdd(&fo[ed.z - node0], 1);
        csr[base + pos] = make_int2(ed.x, ed.y);
    }
}

// =====================================================================
// Propagation (bf16 state): zout = 0.9 * A zin + 0.1 * z0
// =====================================================================
__global__ __launch_bounds__(256) void prop_kernel(
    const int* __restrict__ rowptr, const int2* __restrict__ csr,
    const unsigned short* __restrict__ zin, const unsigned short* __restrict__ z0,
    unsigned short* __restrict__ zout_b, float* __restrict__ zout_f,
    int n, int final_layer)
{
    int lane = threadIdx.x & 63;
    int node = blockIdx.x * 4 + (threadIdx.x >> 6);
    if (node >= n) return;
    int beg = rowptr[node], end = rowptr[node + 1];
    const int sub = lane >> 3;
    const int k8  = lane & 7;

    float acc[8];
#pragma unroll
    for (int i = 0; i < 8; ++i) acc[i] = 0.f;

    for (int b = beg; b < end; b += 64) {
        int e = b + lane;
        int2 ed = (e < end) ? csr[e] : make_int2(0, 0);
        int cnt = end - b; if (cnt > 64) cnt = 64;
        int groups = (cnt + 7) >> 3;
        for (int j = 0; j < groups; ++j) {
            int idx = j * 8 + sub;
            int sj = __shfl(ed.x, idx);
            int wb = __shfl(ed.y, idx);
            if (idx < cnt) {
                float wj = __builtin_bit_cast(float, wb);
                uint4 v = *(const uint4*)(zin + (size_t)sj * 64 + k8 * 8);
                acc[0] += wj * blo(v.x); acc[1] += wj * bhi(v.x);
                acc[2] += wj * blo(v.y); acc[3] += wj * bhi(v.y);
                acc[4] += wj * blo(v.z); acc[5] += wj * bhi(v.z);
                acc[6] += wj * blo(v.w); acc[7] += wj * bhi(v.w);
            }
        }
    }
#pragma unroll
    for (int off = 8; off < 64; off <<= 1) {
#pragma unroll
        for (int i = 0; i < 8; ++i) acc[i] += __shfl_xor(acc[i], off);
    }
    if (sub == 0) {
        uint4 zv = *(const uint4*)(z0 + (size_t)node * 64 + k8 * 8);
        float o0 = 0.9f * acc[0] + 0.1f * blo(zv.x);
        float o1 = 0.9f * acc[1] + 0.1f * bhi(zv.x);
        float o2 = 0.9f * acc[2] + 0.1f * blo(zv.y);
        float o3 = 0.9f * acc[3] + 0.1f * bhi(zv.y);
        float o4 = 0.9f * acc[4] + 0.1f * blo(zv.z);
        float o5 = 0.9f * acc[5] + 0.1f * bhi(zv.z);
        float o6 = 0.9f * acc[6] + 0.1f * blo(zv.w);
        float o7 = 0.9f * acc[7] + 0.1f * bhi(zv.w);
        if (final_layer) {
            float* dp = zout_f + (size_t)node * 64 + k8 * 8;
            *(float4*)dp       = make_float4(o0, o1, o2, o3);
            *(float4*)(dp + 4) = make_float4(o4, o5, o6, o7);
        } else {
            uint4 pv;
            pv.x = f2bu(o0) | (f2bu(o1) << 16);
            pv.y = f2bu(o2) | (f2bu(o3) << 16);
            pv.z = f2bu(o4) | (f2bu(o5) << 16);
            pv.w = f2bu(o6) | (f2bu(o7) << 16);
            *(uint4*)(zout_b + (size_t)node * 64 + k8 * 8) = pv;
        }
    }
}

// =====================================================================
static inline size_t align_up(size_t v, size_t a) { return (v + a - 1) & ~(a - 1); }

extern "C" void kernel_launch(void* const* d_in, const int* in_sizes, int n_in,
                              void* d_out, int out_size, void* d_ws, size_t ws_size,
                              hipStream_t stream)
{
    const float* x     = (const float*)d_in[0];
    const float* W_in  = (const float*)d_in[1];
    const float* b_in  = (const float*)d_in[2];
    const float* W_out = (const float*)d_in[3];
    const float* b_out = (const float*)d_in[4];
    const int*   ei    = (const int*)d_in[5];     // [2,E]: src then dst
    const float* ew    = (const float*)d_in[6];

    const int N = in_sizes[0] / 512;              // 100000
    const int E = in_sizes[6];                    // 3200000
    const int* e_src = ei;
    const int* e_dst = ei + E;

    const int nbuk = (N + 511) >> 9;              // 196
    const int nblk = (E + CSR_CH - 1) / CSR_CH;   // 196

    // ---- workspace carve-up ----
    char* p = (char*)d_ws;
    size_t zbytes = align_up((size_t)N * 64 * sizeof(unsigned short), 256);
    unsigned short* z0b = (unsigned short*)p; p += zbytes;
    unsigned short* Wi_f = (unsigned short*)p; p += align_up(131072 * 2, 256);
    unsigned short* Wo_f = (unsigned short*)p; p += align_up(16384 * 2, 256);
    int2* csr   = (int2*)p; p += align_up((size_t)E * 8, 256);
    int* rowptr = (int*)p;  p += align_up((size_t)(N + 1) * 4, 256);
    int* M      = (int*)p;  p += align_up((size_t)nblk * nbuk * 4, 256);
    int* bucketBase = (int*)p; p += align_up((size_t)(nbuk + 1) * 4, 256);
    int4* tmp   = (int4*)p; p += align_up((size_t)E * 16, 256);
    unsigned short* zA = (unsigned short*)tmp;    // overlay (tmp dead after fine_sort)
    unsigned short* zB = zA + (size_t)N * 64;

    // ---- weights -> bf16 fragment order, then MLP -> z0 (bf16) ----
    wprep<<<(131072 + 16384 + 255) / 256, 256, 0, stream>>>(W_in, W_out, Wi_f, Wo_f);
    mlp<<<(N + 63) / 64, 256, 0, stream>>>(x, Wi_f, b_in, Wo_f, b_out, z0b, N);

    // ---- CSR build: 2-level counting sort ----
    coarse_hist<<<nblk, 256, 0, stream>>>(e_dst, M, E, nbuk);
    bucket_scan<<<1, 256, 0, stream>>>(M, bucketBase, nblk, nbuk);
    coarse_scatter<<<nblk, 256, 0, stream>>>(e_src, e_dst, ew, M, tmp, E, nbuk);
    fine_sort<<<nbuk, 256, 0, stream>>>(tmp, bucketBase, csr, rowptr, N, E);

    // ---- 10 propagation layers ----
    float* out_f = (float*)d_out;
    int pgrid = (N + 3) / 4;
    for (int i = 0; i < 10; ++i) {
        const unsigned short* zin = (i == 0) ? z0b : ((i & 1) ? zA : zB);
        unsigned short* zoutb = (i & 1) ? zB : zA;
        prop_kernel<<<pgrid, 256, 0, stream>>>(rowptr, csr, zin, z0b,
                                               zoutb, out_f, N, (i == 9) ? 1 : 0);
    }
}